// Round 1
// baseline (61.962 us; speedup 1.0000x reference)
//
#include <hip/hip_runtime.h>

#define TBLK 64
#define NBINS 256
#define EPSF 1e-12f

// One 256-thread block per 64x64 tile. 8192 tiles.
__global__ __launch_bounds__(256) void entropy_kernel(const float* __restrict__ x,
                                                      float* __restrict__ ent) {
    const int b  = blockIdx.x;       // (nc)*16 + bh*4 + bw
    const int nc = b >> 4;
    const int bh = (b >> 2) & 3;
    const int bw = b & 3;
    const float* base = x + ((size_t)nc * 256 + (size_t)bh * 64) * 256 + (size_t)bw * 64;

    const int t    = threadIdx.x;
    const int lane = t & 63;
    const int wave = t >> 6;

    __shared__ float smin[4], smax[4];
    __shared__ float ssum[4];
    __shared__ unsigned int hist[NBINS];

    // ---- load 16 elems/thread, local min/max ----
    float4 v[4];
    float lmin = INFINITY, lmax = -INFINITY;
#pragma unroll
    for (int k = 0; k < 4; ++k) {
        int idx = t + (k << 8);          // 0..1023 float4 index within tile
        int row = idx >> 4;              // 64 rows, 16 float4 per row
        int c4  = idx & 15;
        v[k] = *reinterpret_cast<const float4*>(base + (size_t)row * 256 + c4 * 4);
        lmin = fminf(lmin, fminf(fminf(v[k].x, v[k].y), fminf(v[k].z, v[k].w)));
        lmax = fmaxf(lmax, fmaxf(fmaxf(v[k].x, v[k].y), fmaxf(v[k].z, v[k].w)));
    }
    // wave64 butterfly reduce
#pragma unroll
    for (int off = 32; off > 0; off >>= 1) {
        lmin = fminf(lmin, __shfl_xor(lmin, off));
        lmax = fmaxf(lmax, __shfl_xor(lmax, off));
    }
    if (lane == 0) { smin[wave] = lmin; smax[wave] = lmax; }
    hist[t] = 0u;
    __syncthreads();

    const float bmin  = fminf(fminf(smin[0], smin[1]), fminf(smin[2], smin[3]));
    const float bmax  = fmaxf(fmaxf(smax[0], smax[1]), fmaxf(smax[2], smax[3]));
    const float width = (bmax - bmin) * (1.0f / NBINS);
    const float wsafe = (width > 0.0f) ? width : 1.0f;

    // ---- histogram (IEEE div to match reference binning exactly) ----
#pragma unroll
    for (int k = 0; k < 4; ++k) {
        float vals[4] = {v[k].x, v[k].y, v[k].z, v[k].w};
#pragma unroll
        for (int j = 0; j < 4; ++j) {
            float f   = floorf((vals[j] - bmin) / wsafe);
            int   bin = (int)fminf(fmaxf(f, 0.0f), 255.0f);
            atomicAdd(&hist[bin], 1u);
        }
    }
    __syncthreads();

    // ---- entropy: one bin per thread ----
    float p = (float)hist[t] / (4096.0f * wsafe) + EPSF;
    float s = p;
#pragma unroll
    for (int off = 32; off > 0; off >>= 1) s += __shfl_xor(s, off);
    if (lane == 0) ssum[wave] = s;
    __syncthreads();
    const float tot = ssum[0] + ssum[1] + ssum[2] + ssum[3];
    const float pn  = p / tot;
    float e = pn * log2f(pn);
#pragma unroll
    for (int off = 32; off > 0; off >>= 1) e += __shfl_xor(e, off);
    __syncthreads();                 // done reading ssum (tot) before reuse
    if (lane == 0) ssum[wave] = e;
    __syncthreads();
    if (t == 0) ent[b] = -(ssum[0] + ssum[1] + ssum[2] + ssum[3]);
}

// Half-pixel bilinear upsample (4x4 -> 256x256 per nc), float4 stores.
__global__ __launch_bounds__(256) void upsample_kernel(const float* __restrict__ ent,
                                                       float* __restrict__ out) {
    const int total4 = 8 * 64 * 256 * 64;   // 8388608 float4s
    for (int i = blockIdx.x * blockDim.x + threadIdx.x; i < total4;
         i += gridDim.x * blockDim.x) {
        int x4 = i & 63;
        int y  = (i >> 6) & 255;
        int nc = i >> 14;
        const float* e = ent + nc * 16;

        float fy  = (y + 0.5f) * 0.015625f - 0.5f;   // /64
        float fiy = floorf(fy);
        float wy  = fy - fiy;
        int   iy  = (int)fiy;
        int   y0  = max(iy, 0), y1 = min(iy + 1, 3);

        float r0[4], r1[4];
#pragma unroll
        for (int j = 0; j < 4; ++j) { r0[j] = e[y0 * 4 + j]; r1[j] = e[y1 * 4 + j]; }

        float4 o;
        float* op = &o.x;
#pragma unroll
        for (int j = 0; j < 4; ++j) {
            int   xx  = (x4 << 2) + j;
            float fx  = (xx + 0.5f) * 0.015625f - 0.5f;
            float fix = floorf(fx);
            float wx  = fx - fix;
            int   ix  = (int)fix;
            int   x0  = max(ix, 0), x1 = min(ix + 1, 3);
            float top = r0[x0] * (1.0f - wx) + r0[x1] * wx;
            float bot = r1[x0] * (1.0f - wx) + r1[x1] * wx;
            op[j] = top * (1.0f - wy) + bot * wy;
        }
        reinterpret_cast<float4*>(out)[i] = o;
    }
}

extern "C" void kernel_launch(void* const* d_in, const int* in_sizes, int n_in,
                              void* d_out, int out_size, void* d_ws, size_t ws_size,
                              hipStream_t stream) {
    const float* x   = (const float*)d_in[0];
    float*       out = (float*)d_out;
    float*       ent = (float*)d_ws;     // 8192 floats = 32 KB

    entropy_kernel<<<8192, 256, 0, stream>>>(x, ent);
    upsample_kernel<<<2048, 256, 0, stream>>>(ent, out);
}

// Round 3
// 51.349 us; speedup vs baseline: 1.2067x; 1.2067x over previous
//
#include <hip/hip_runtime.h>

#define NBINS 256
#define EPSF 1e-12f

typedef float v4f __attribute__((ext_vector_type(4)));

// One 256-thread block per 64x64 tile. 8192 tiles.
__global__ __launch_bounds__(256) void entropy_kernel(const float* __restrict__ x,
                                                      float* __restrict__ ent) {
    const int b  = blockIdx.x;       // (nc)*16 + bh*4 + bw
    const int nc = b >> 4;
    const int bh = (b >> 2) & 3;
    const int bw = b & 3;
    const float* base = x + ((size_t)nc * 256 + (size_t)bh * 64) * 256 + (size_t)bw * 64;

    const int t    = threadIdx.x;
    const int lane = t & 63;
    const int wave = t >> 6;

    __shared__ float smin[4], smax[4];
    __shared__ float ssum[4];
    __shared__ unsigned int hist[4][NBINS];   // per-wave privatized

    // ---- load 16 elems/thread (nontemporal: streamed once), local min/max ----
    v4f v[4];
    float lmin = INFINITY, lmax = -INFINITY;
#pragma unroll
    for (int k = 0; k < 4; ++k) {
        int idx = t + (k << 8);          // 0..1023 float4 index within tile
        int row = idx >> 4;              // 64 rows, 16 float4 per row
        int c4  = idx & 15;
        v[k] = __builtin_nontemporal_load(
                   reinterpret_cast<const v4f*>(base + (size_t)row * 256 + c4 * 4));
        lmin = fminf(lmin, fminf(fminf(v[k].x, v[k].y), fminf(v[k].z, v[k].w)));
        lmax = fmaxf(lmax, fmaxf(fmaxf(v[k].x, v[k].y), fmaxf(v[k].z, v[k].w)));
    }
    // wave64 butterfly reduce
#pragma unroll
    for (int off = 32; off > 0; off >>= 1) {
        lmin = fminf(lmin, __shfl_xor(lmin, off));
        lmax = fmaxf(lmax, __shfl_xor(lmax, off));
    }
    if (lane == 0) { smin[wave] = lmin; smax[wave] = lmax; }
    hist[0][t] = 0u; hist[1][t] = 0u; hist[2][t] = 0u; hist[3][t] = 0u;
    __syncthreads();

    const float bmin  = fminf(fminf(smin[0], smin[1]), fminf(smin[2], smin[3]));
    const float bmax  = fmaxf(fmaxf(smax[0], smax[1]), fmaxf(smax[2], smax[3]));
    const float width = (bmax - bmin) * (1.0f / NBINS);
    const float wsafe = (width > 0.0f) ? width : 1.0f;
    const float inv   = 1.0f / wsafe;     // one IEEE div; recip-mul binning below

    // ---- histogram into this wave's private copy ----
    unsigned int* h = hist[wave];
#pragma unroll
    for (int k = 0; k < 4; ++k) {
        float vals[4] = {v[k].x, v[k].y, v[k].z, v[k].w};
#pragma unroll
        for (int j = 0; j < 4; ++j) {
            float f   = floorf((vals[j] - bmin) * inv);
            int   bin = (int)fminf(fmaxf(f, 0.0f), 255.0f);
            atomicAdd(&h[bin], 1u);
        }
    }
    __syncthreads();

    // ---- entropy: one bin per thread ----
    const float cnt = (float)(hist[0][t] + hist[1][t] + hist[2][t] + hist[3][t]);
    float p = cnt / (4096.0f * wsafe) + EPSF;   // IEEE div to match reference
    float s = p;
#pragma unroll
    for (int off = 32; off > 0; off >>= 1) s += __shfl_xor(s, off);
    if (lane == 0) ssum[wave] = s;
    __syncthreads();
    const float tot = ssum[0] + ssum[1] + ssum[2] + ssum[3];
    const float pn  = p / tot;
    float e = pn * log2f(pn);
#pragma unroll
    for (int off = 32; off > 0; off >>= 1) e += __shfl_xor(e, off);
    __syncthreads();                 // done reading ssum (tot) before reuse
    if (lane == 0) ssum[wave] = e;
    __syncthreads();
    if (t == 0) ent[b] = -(ssum[0] + ssum[1] + ssum[2] + ssum[3]);
}

// Half-pixel bilinear upsample (4x4 -> 256x256 per nc).
// tid -> (x4, y) fixed; the unrolled loop walks nc only, so all weight math
// is hoisted. Horizontal blend = dot(row, wv_j) with precomputed per-lane
// weight vectors (ix is uniform over each lane's 4 pixels since boundaries
// 32/96/160/224 are multiples of 4).
__global__ __launch_bounds__(256) void upsample_kernel(const float* __restrict__ ent,
                                                       float* __restrict__ out) {
    const int tid = blockIdx.x * blockDim.x + threadIdx.x;   // 0..524287
    const int x4  = tid & 63;
    const int y   = (tid >> 6) & 255;
    const int nc0 = tid >> 14;                                // 0..31

    // vertical weights (uniform across the wave)
    const float fy  = (y + 0.5f) * 0.015625f - 0.5f;
    const float fiy = floorf(fy);
    const float wy  = fy - fiy;
    const int   iy  = (int)fiy;
    const int   y0  = max(iy, 0), y1 = min(iy + 1, 3);
    const float wy0 = 1.0f - wy;

    // horizontal: ix uniform over this lane's 4 pixels
    const int ix = (int)floorf(((x4 << 2) + 0.5f) * 0.015625f - 0.5f);
    const int x0 = max(ix, 0), x1 = min(ix + 1, 3);

    v4f wv[4];
#pragma unroll
    for (int j = 0; j < 4; ++j) {
        const float fx = ((x4 << 2) + j + 0.5f) * 0.015625f - 0.5f;
        const float wx = fx - floorf(fx);
        const float a  = 1.0f - wx, bb = wx;
        wv[j].x = ((x0 == 0) ? a : 0.0f) + ((x1 == 0) ? bb : 0.0f);
        wv[j].y = ((x0 == 1) ? a : 0.0f) + ((x1 == 1) ? bb : 0.0f);
        wv[j].z = ((x0 == 2) ? a : 0.0f) + ((x1 == 2) ? bb : 0.0f);
        wv[j].w = ((x0 == 3) ? a : 0.0f) + ((x1 == 3) ? bb : 0.0f);
    }

    const v4f* e4 = reinterpret_cast<const v4f*>(ent);  // 4 v4f rows per nc
#pragma unroll
    for (int it = 0; it < 16; ++it) {
        const int nc = nc0 + (it << 5);
        const v4f r0 = e4[nc * 4 + y0];
        const v4f r1 = e4[nc * 4 + y1];
        v4f rv = r0 * wy0 + r1 * wy;
        v4f o;
        o.x = rv.x * wv[0].x + rv.y * wv[0].y + rv.z * wv[0].z + rv.w * wv[0].w;
        o.y = rv.x * wv[1].x + rv.y * wv[1].y + rv.z * wv[1].z + rv.w * wv[1].w;
        o.z = rv.x * wv[2].x + rv.y * wv[2].y + rv.z * wv[2].z + rv.w * wv[2].w;
        o.w = rv.x * wv[3].x + rv.y * wv[3].y + rv.z * wv[3].z + rv.w * wv[3].w;
        __builtin_nontemporal_store(o, reinterpret_cast<v4f*>(out) +
                                           ((size_t)nc << 14) + (y << 6) + x4);
    }
}

extern "C" void kernel_launch(void* const* d_in, const int* in_sizes, int n_in,
                              void* d_out, int out_size, void* d_ws, size_t ws_size,
                              hipStream_t stream) {
    const float* x   = (const float*)d_in[0];
    float*       out = (float*)d_out;
    float*       ent = (float*)d_ws;     // 8192 floats = 32 KB

    entropy_kernel<<<8192, 256, 0, stream>>>(x, ent);
    upsample_kernel<<<2048, 256, 0, stream>>>(ent, out);
}